// Round 9
// baseline (1699.551 us; speedup 1.0000x reference)
//
#include <hip/hip_runtime.h>
#include <stdint.h>

// Problem dims
#define TS  256
#define CTS 512
#define BB  64
#define HH  512
#define KK  10

typedef short short8 __attribute__((ext_vector_type(8)));
typedef float floatx4 __attribute__((ext_vector_type(4)));

__device__ __forceinline__ unsigned short f2bf(float f) {
  unsigned u = __float_as_uint(f);
  unsigned r = (u + 0x7fffu + ((u >> 16) & 1u)) >> 16;  // RNE
  return (unsigned short)r;
}

// ---------------------------------------------------------------------------
// K1: Wcat [2048][1024] bf16.
// Row groups of 512: g0 = r-gate [W_hh_r | W_ih_r]; g1 = z-gate [W_hh_z | W_ih_z];
// g2 = i_n [0 | W_ih_n]; g3 = h_n [W_hh_n | 0]. (n = tanh(i_n + r*h_n) needs the split)
__global__ void k_wcat(const float* __restrict__ W_ih, const float* __restrict__ W_hh,
                       unsigned short* __restrict__ Wcat) {
  int idx = blockIdx.x * 256 + threadIdx.x;  // 2048*1024 total
  int r = idx >> 10, c = idx & 1023;
  int g = r >> 9, j = r & 511;
  float v;
  if (g == 0)      v = (c < 512) ? W_hh[j * 512 + c]          : W_ih[j * 512 + (c - 512)];
  else if (g == 1) v = (c < 512) ? W_hh[(512 + j) * 512 + c]  : W_ih[(512 + j) * 512 + (c - 512)];
  else if (g == 2) v = (c < 512) ? 0.f                        : W_ih[(1024 + j) * 512 + (c - 512)];
  else             v = (c < 512) ? W_hh[(1024 + j) * 512 + c] : 0.f;
  Wcat[idx] = f2bf(v);
}

// ---------------------------------------------------------------------------
// K2: G[t*64+b][30] = exp(x_t[b] @ {Wa;Wb;Wk}.T + bias). One wave per (t,b) row.
__global__ void k_abk(const float* __restrict__ inp,
                      const float* __restrict__ Wa, const float* __restrict__ ba,
                      const float* __restrict__ Wb, const float* __restrict__ bvb,
                      const float* __restrict__ Wk, const float* __restrict__ bk,
                      float* __restrict__ G) {
  int row = blockIdx.x;                 // t*64 + b
  int lane = threadIdx.x;               // 0..63
  int j = lane & 31, half = lane >> 5;  // j = output idx, half = K-half
  const float* Wrow; float bias;
  if (j < 10)      { Wrow = Wa + j * 512;        bias = ba[j]; }
  else if (j < 20) { Wrow = Wb + (j - 10) * 512; bias = bvb[j - 10]; }
  else if (j < 30) { Wrow = Wk + (j - 20) * 512; bias = bk[j - 20]; }
  else             { Wrow = Wa;                  bias = 0.f; }
  const float4* x4 = (const float4*)(inp + row * 512 + half * 256);
  const float4* w4 = (const float4*)(Wrow + half * 256);
  float acc = 0.f;
#pragma unroll 8
  for (int i = 0; i < 64; ++i) {
    float4 a = x4[i], w = w4[i];
    acc += a.x * w.x + a.y * w.y + a.z * w.z + a.w * w.w;
  }
  acc += __shfl_down(acc, 32, 64);  // fold the two K-halves
  if (lane < 30) G[row * 30 + lane] = __expf(acc + bias);
}

// ---------------------------------------------------------------------------
// K3: k_t cumsum over t for each (b,k) — parallel Hillis-Steele scan per b.
__global__ __launch_bounds__(256) void k_cumsum(
    const float* __restrict__ G, const float* __restrict__ att_init,
    float* __restrict__ out_k) {
  int b = blockIdx.x;       // 64 blocks
  int t = threadIdx.x;      // 256 = TS
  __shared__ float sb[2][256];
  for (int k = 0; k < KK; ++k) {
    float v = G[(t * BB + b) * 30 + 20 + k];
    sb[0][t] = v;
    __syncthreads();
    int src = 0;
#pragma unroll
    for (int d = 1; d < 256; d <<= 1) {
      float add = (t >= d) ? sb[src][t - d] : 0.f;
      float cur = sb[src][t];
      __syncthreads();
      sb[1 - src][t] = cur + add;
      src = 1 - src;
      __syncthreads();
    }
    out_k[(t * BB + b) * KK + k] = att_init[b * KK + k] + sb[src][t];
    __syncthreads();
  }
}

// ---------------------------------------------------------------------------
// K4: phi[b][t][s] = sum_k a*exp(-b*(k_t - s)^2), stored bf16.
__global__ void k_phi(const float* __restrict__ G, const float* __restrict__ attk,
                      unsigned short* __restrict__ phi_bf) {
  int t = blockIdx.x, b = blockIdx.y;
  int row = t * BB + b;
  float a[10], bv[10], kt[10];
#pragma unroll
  for (int k = 0; k < 10; ++k) {
    a[k]  = G[row * 30 + k];
    bv[k] = G[row * 30 + 10 + k];
    kt[k] = attk[row * KK + k];
  }
#pragma unroll
  for (int e = 0; e < 2; ++e) {
    int s = threadIdx.x + e * 256;
    float fs = (float)s;
    float ph = 0.f;
#pragma unroll
    for (int k = 0; k < 10; ++k) {
      float d = kt[k] - fs;
      ph += a[k] * __expf(-bv[k] * d * d);
    }
    phi_bf[(b * TS + t) * CTS + s] = f2bf(ph);
  }
}

// ---------------------------------------------------------------------------
// K5: att_w[t][b][h] = sum_s phi[b][t][s] * c_inp[s][b][h]. Per-b MFMA GEMM.
// t0-FUSED (round-6, passed): grid (8,64); 4 t0-tiles loop inside so each
// c_inp Bt tile is staged once instead of 4x.
__global__ __launch_bounds__(256) void k_attw(
    const float* __restrict__ c_inp, const unsigned short* __restrict__ phi_bf,
    float* __restrict__ out_w, unsigned short* __restrict__ attw_bf) {
  int h0 = blockIdx.x * 64;
  int b  = blockIdx.y;
  int tid = threadIdx.x;
  int lane = tid & 63, wv = tid >> 6;
  int x = lane & 15, q = lane >> 4;
  __shared__ __align__(16) unsigned short Bt[64 * 40];  // [h_local][s_local], pad 40
  floatx4 acc[4][4];                                    // [t0][mt]
#pragma unroll
  for (int t0 = 0; t0 < 4; ++t0)
#pragma unroll
    for (int m = 0; m < 4; ++m) acc[t0][m] = (floatx4){0.f, 0.f, 0.f, 0.f};
  int s_l = tid >> 3, h8 = (tid & 7) * 8;
  for (int ss = 0; ss < 16; ++ss) {
    int s0 = ss * 32;
    const float* src = c_inp + ((s0 + s_l) * BB + b) * HH + h0 + h8;
    float4 v0 = *(const float4*)src;
    float4 v1 = *(const float4*)(src + 4);
    Bt[(h8 + 0) * 40 + s_l] = f2bf(v0.x);
    Bt[(h8 + 1) * 40 + s_l] = f2bf(v0.y);
    Bt[(h8 + 2) * 40 + s_l] = f2bf(v0.z);
    Bt[(h8 + 3) * 40 + s_l] = f2bf(v0.w);
    Bt[(h8 + 4) * 40 + s_l] = f2bf(v1.x);
    Bt[(h8 + 5) * 40 + s_l] = f2bf(v1.y);
    Bt[(h8 + 6) * 40 + s_l] = f2bf(v1.z);
    Bt[(h8 + 7) * 40 + s_l] = f2bf(v1.w);
    __syncthreads();
    short8 bfrag = *(const short8*)(Bt + (wv * 16 + x) * 40 + q * 8);
#pragma unroll
    for (int t0 = 0; t0 < 4; ++t0)
#pragma unroll
      for (int mt = 0; mt < 4; ++mt) {
        short8 af = *(const short8*)(
            phi_bf + ((size_t)b * TS + t0 * 64 + mt * 16 + x) * CTS + s0 + q * 8);
        acc[t0][mt] = __builtin_amdgcn_mfma_f32_16x16x32_bf16(af, bfrag, acc[t0][mt], 0, 0, 0);
      }
    __syncthreads();
  }
#pragma unroll
  for (int t0 = 0; t0 < 4; ++t0)
#pragma unroll
    for (int mt = 0; mt < 4; ++mt)
#pragma unroll
      for (int r = 0; r < 4; ++r) {
        int t_l = t0 * 64 + mt * 16 + q * 4 + r;   // C/D: row = quad*4+reg
        int row = t_l * BB + b;
        int col = h0 + wv * 16 + x;                // C/D: col = lane&15
        float v = acc[t0][mt][r];
        out_w[row * HH + col] = v;
        attw_bf[row * HH + col] = f2bf(v);
      }
}

// ---------------------------------------------------------------------------
// K6: persistent GRU. SYNC SKELETON = round-0 VERBATIM (r7-proven live).
// COMPUTE = gang decomposition (r7-proven): wave wv owns batches
// [16wv,16wv+16), WG owns j [16w,16w+16), gates in-lane.
// r9 = r8-intent with the r3/r5 HW-VERIFIED [C]/[D] sequence restored:
// LDA(0..7); vmcnt(0); sched_barrier(0); LDA(8..15); MFMA(0..7); vmcnt(0);
// sched_barrier(0); MFMA(8..15). (r8 dropped the sched_barriers -> hipcc may
// hoist register-only MFMA past the inline-asm waitcnt [known hazard]; iter-0
// then feeds uninitialized VGPRs -> NaN cascade.) afw refill back inside [A]
// (r7 interleave; the poll's embedded vmcnt(0) drains it).
#define WAITVM(N) asm volatile("s_waitcnt vmcnt(" #N ")" ::: "memory")
#define SFENCE() __builtin_amdgcn_sched_barrier(0)
#define LDA(k, off)                                                       \
  asm volatile("global_load_dwordx4 %0, %1, off offset:" #off " sc0"      \
               : "=v"(afr[k]) : "v"(hsrc) : "memory")
#define MF3H(k)                                                                        \
  ar_ = __builtin_amdgcn_mfma_f32_16x16x32_bf16(afr[k], wfrag[0][k], ar_, 0, 0, 0);    \
  az_ = __builtin_amdgcn_mfma_f32_16x16x32_bf16(afr[k], wfrag[1][k], az_, 0, 0, 0);    \
  nh_ = __builtin_amdgcn_mfma_f32_16x16x32_bf16(afr[k], wfrag[2][k], nh_, 0, 0, 0)

__global__ __launch_bounds__(256, 1) void k_seq(
    const unsigned short* __restrict__ attw_bf, const unsigned short* __restrict__ Wcat,
    const float* __restrict__ gru_init, const float* __restrict__ b_ih,
    const float* __restrict__ b_hh, unsigned short* __restrict__ h_buf,
    unsigned* __restrict__ flags, unsigned* __restrict__ ctl,
    float* __restrict__ hid_out) {
  // 96 KB LDS (Swih + pad) -> 1 WG/CU so the 32 workers each own a CU.
  // Volatile store keeps the pad allocation from being DCE'd.
  __shared__ __align__(16) unsigned short Swih[24576];    // 48 KB W_ih frags
  __shared__ __align__(16) unsigned short pad[24576];     // 48 KB residency pad
  __shared__ int sh_slot;
  const int tid = threadIdx.x;
  if (tid == 0) ((volatile unsigned short*)pad)[0] = 0;

  // --- XCD-local slot discovery (round-0 VERBATIM) ---
  if (tid == 0) {
    unsigned xcc = __builtin_amdgcn_s_getreg(6164) & 0xfu;  // hwreg(HW_REG_XCC_ID,0,4)
    unsigned s = atomicAdd(&ctl[1 + xcc], 1u);
    if (s == 31u) atomicCAS(&ctl[0], 0u, xcc + 1u);         // first full bucket wins
    unsigned ch;
    while ((ch = __hip_atomic_load(&ctl[0], __ATOMIC_RELAXED,
                                   __HIP_MEMORY_SCOPE_AGENT)) == 0u) {}
    sh_slot = (ch - 1u == xcc && s < 32u) ? (int)s : -1;
  }
  __syncthreads();
  const int w = sh_slot;
  if (w < 0) return;  // not a worker

  const int lane = tid & 63, wv = tid >> 6;
  const int x = lane & 15, q = lane >> 4;
  const int j0 = w * 16;          // this WG's 16 h-columns
  const int b0 = wv * 16;         // this wave's gang: 16 batches
  const int bq = b0 + q * 4;      // C/D row base for this lane
  const int jx = j0 + x;

  // --- stage W_ih frags (gates r,z,i_n; Wcat K-cols 512..1023) into Swih,
  //     frag-major (r7-verified): short addr = fidx*8,
  //     fidx = ((g*16+kk)*4+qq)*16 + jl.
#pragma unroll
  for (int i = 0; i < 12; ++i) {
    int fidx = i * 256 + tid;          // 0..3071
    int jl = fidx & 15;
    int rest = fidx >> 4;              // (g*16+kk)*4+qq
    int qq = rest & 3;
    int rest2 = rest >> 2;             // g*16+kk
    int kk = rest2 & 15, g = rest2 >> 4;
    *(short8*)(Swih + (size_t)fidx * 8) =
        *(const short8*)(Wcat + (size_t)(g * 512 + j0 + jl) * 1024 + 512 + kk * 32 + qq * 8);
  }

  // --- W_hh B-frags into regs: gates r(g0), z(g1), h_n(g3); Wcat K-cols 0..511 ---
  short8 wfrag[3][16];
#pragma unroll
  for (int gi = 0; gi < 3; ++gi) {
    const int g = (gi == 2) ? 3 : gi;
    const unsigned short* wr = Wcat + (size_t)(g * 512 + jx) * 1024 + q * 8;
#pragma unroll
    for (int kk = 0; kk < 16; ++kk)
      wfrag[gi][kk] = *(const short8*)(wr + kk * 32);
  }
  const float biasR  = b_ih[jx] + b_hh[jx];
  const float biasZ  = b_ih[512 + jx] + b_hh[512 + jx];
  const float biasNW = b_ih[1024 + jx];
  const float biasNH = b_hh[1024 + jx];

  float hp[4];
#pragma unroll
  for (int r = 0; r < 4; ++r) hp[r] = gru_init[(size_t)(bq + r) * HH + jx];

  // --- publish h_0 (plain packed-dword stores, r7-verified packing), then
  //     round-0 VERBATIM drain/barrier/flag ---
#pragma unroll
  for (int r = 0; r < 4; ++r) {
    float ov = __shfl(hp[r], lane ^ 1, 64);
    if ((x & 1) == 0)
      *(unsigned*)(h_buf + (size_t)(bq + r) * HH + jx) =
          (unsigned)f2bf(hp[r]) | ((unsigned)f2bf(ov) << 16);
  }
  asm volatile("" ::: "memory");
  __builtin_amdgcn_s_waitcnt(0);   // stores L2-committed
  __syncthreads();                 // also covers Swih staging
  if (tid == 0) flags[w * 32] = 1u;
  asm volatile("" ::: "memory");

  // --- attw(0) A-frags prefetch (plain loads; L1/L2) ---
  short8 afw[16];
  {
    const unsigned short* ap = attw_bf + (size_t)(b0 + x) * HH + q * 8;
#pragma unroll
    for (int kk = 0; kk < 16; ++kk) afw[kk] = *(const short8*)(ap + kk * 32);
  }

#pragma unroll 1
  for (int t = 0; t < TS; ++t) {
    // --- [A] w-side GEMM (h-independent) + afw refill for t+1 (r7 verbatim) ---
    floatx4 ar_ = {biasR, biasR, biasR, biasR};
    floatx4 az_ = {biasZ, biasZ, biasZ, biasZ};
    floatx4 nw_ = {biasNW, biasNW, biasNW, biasNW};
    floatx4 nh_ = {biasNH, biasNH, biasNH, biasNH};
    {
      int tn = (t + 1 < TS) ? t + 1 : t;
      const unsigned short* awn = attw_bf + ((size_t)tn * BB + b0 + x) * HH + q * 8;
      const unsigned short* fb = Swih + (size_t)q * 128 + x * 8;
#pragma unroll
      for (int kk = 0; kk < 16; ++kk) {
        short8 a = afw[kk];
        ar_ = __builtin_amdgcn_mfma_f32_16x16x32_bf16(
            a, *(const short8*)(fb + kk * 512), ar_, 0, 0, 0);
        az_ = __builtin_amdgcn_mfma_f32_16x16x32_bf16(
            a, *(const short8*)(fb + kk * 512 + 8192), az_, 0, 0, 0);
        nw_ = __builtin_amdgcn_mfma_f32_16x16x32_bf16(
            a, *(const short8*)(fb + kk * 512 + 16384), nw_, 0, 0, 0);
        afw[kk] = *(const short8*)(awn + kk * 32);   // refill (consumed next step)
      }
    }

    // --- [B] poll: round-0 VERBATIM (unbounded, tid<32, sc0) + barrier.
    //     The poll's vmcnt(0) also drains this wave's afw refills. ---
    if (tid < 32) {
      const unsigned* fp = flags + tid * 32;
      unsigned fv;
      do {
        asm volatile("global_load_dword %0, %1, off sc0\n\ts_waitcnt vmcnt(0)"
                     : "=v"(fv)
                     : "v"((unsigned long long)(uintptr_t)fp)
                     : "memory");
      } while (fv < (unsigned)(t + 1));
    }
    __syncthreads();

    // --- [C]/[D]: r3/r5 HW-VERIFIED sequence — split 8/8, vmcnt(0)+SFENCE ---
    const unsigned long long hsrc = (unsigned long long)(uintptr_t)(
        h_buf + (size_t)(t & 3) * (BB * HH) + (size_t)(b0 + x) * HH + q * 8);
    short8 afr[16];
    LDA(0, 0);   LDA(1, 64);  LDA(2, 128); LDA(3, 192);
    LDA(4, 256); LDA(5, 320); LDA(6, 384); LDA(7, 448);
    WAITVM(0);   // first 8 resident
    SFENCE();
    LDA(8, 512);  LDA(9, 576);  LDA(10, 640); LDA(11, 704);
    LDA(12, 768); LDA(13, 832); LDA(14, 896); LDA(15, 960);
    MF3H(0); MF3H(1); MF3H(2); MF3H(3); MF3H(4); MF3H(5); MF3H(6); MF3H(7);
    WAITVM(0);   // second 8 resident
    SFENCE();
    MF3H(8); MF3H(9); MF3H(10); MF3H(11); MF3H(12); MF3H(13); MF3H(14); MF3H(15);

    // --- gates: everything for (b,j) lives in this lane (r7-verified) ---
    float hn[4];
#pragma unroll
    for (int r = 0; r < 4; ++r) {
      float rr = 1.f / (1.f + __expf(-ar_[r]));
      float zz = 1.f / (1.f + __expf(-az_[r]));
      float e2 = __expf(2.f * (nw_[r] + rr * nh_[r]));
      float nn = 1.f - 2.f / (e2 + 1.f);          // tanh
      hn[r] = (1.f - zz) * nn + zz * hp[r];
    }

    // --- [E] publish h_{t+1} (plain packed dwords) + round-0 VERBATIM
    //     drain/barrier/flag ---
    unsigned short* hdst = h_buf + (size_t)((t + 1) & 3) * (BB * HH);
#pragma unroll
    for (int r = 0; r < 4; ++r) {
      float ov = __shfl(hn[r], lane ^ 1, 64);
      if ((x & 1) == 0)
        *(unsigned*)(hdst + (size_t)(bq + r) * HH + jx) =
            (unsigned)f2bf(hn[r]) | ((unsigned)f2bf(ov) << 16);
    }
    asm volatile("" ::: "memory");
    __builtin_amdgcn_s_waitcnt(0);   // publishes L2-committed
    __syncthreads();
    if (tid == 0) flags[w * 32] = (unsigned)(t + 2);
    asm volatile("" ::: "memory");

    // --- [F] f32 outputs (post-flag, off the critical path) ---
#pragma unroll
    for (int r = 0; r < 4; ++r) {
      float ov = __shfl(hn[r], lane ^ 1, 64);
      if ((x & 1) == 0)
        *(float2*)(hid_out + ((size_t)t * BB + bq + r) * HH + jx) =
            make_float2(hn[r], ov);
    }
#pragma unroll
    for (int r = 0; r < 4; ++r) hp[r] = hn[r];
  }
}

// ---------------------------------------------------------------------------
extern "C" void kernel_launch(void* const* d_in, const int* in_sizes, int n_in,
                              void* d_out, int out_size, void* d_ws, size_t ws_size,
                              hipStream_t stream) {
  const float* c_inp    = (const float*)d_in[0];
  const float* inp      = (const float*)d_in[1];
  const float* gru_init = (const float*)d_in[2];
  const float* att_init = (const float*)d_in[3];
  const float* Wa = (const float*)d_in[4];
  const float* ba = (const float*)d_in[5];
  const float* Wb = (const float*)d_in[6];
  const float* bvb = (const float*)d_in[7];
  const float* Wk = (const float*)d_in[8];
  const float* bk = (const float*)d_in[9];
  const float* W_ih = (const float*)d_in[10];
  const float* b_ih = (const float*)d_in[11];
  const float* W_hh = (const float*)d_in[12];
  const float* b_hh = (const float*)d_in[13];

  float* out_h = (float*)d_out;                     // hiddens [256,64,512]
  float* out_k = out_h + TS * BB * HH;              // att_k   [256,64,10]
  float* out_w = out_k + TS * BB * KK;              // att_w   [256,64,512]

  char* ws = (char*)d_ws;
  float* G             = (float*)(ws);                              //  2 MB used
  unsigned short* Wcat = (unsigned short*)(ws + 8388608);           //  4 MB
  unsigned short* phi  = (unsigned short*)(ws + 12582912);          // 16 MB
  unsigned short* awb  = (unsigned short*)(ws + 29360128);          // 16 MB
  unsigned short* hbuf = (unsigned short*)(ws + 46137344);          // 256 KB (4 slots)
  unsigned* flags      = (unsigned*)(ws + 46399488);                //  4 KB
  unsigned* ctl        = (unsigned*)(ws + 46403584);                //  64 B

  hipMemsetAsync(flags, 0, 8192, stream);  // flags + ctl
  hipLaunchKernelGGL(k_wcat, dim3(8192), dim3(256), 0, stream, W_ih, W_hh, Wcat);
  hipLaunchKernelGGL(k_abk, dim3(TS * BB), dim3(64), 0, stream,
                     inp, Wa, ba, Wb, bvb, Wk, bk, G);
  hipLaunchKernelGGL(k_cumsum, dim3(BB), dim3(256), 0, stream, G, att_init, out_k);
  hipLaunchKernelGGL(k_phi, dim3(TS, BB), dim3(256), 0, stream, G, out_k, phi);
  hipLaunchKernelGGL(k_attw, dim3(8, BB), dim3(256), 0, stream, c_inp, phi, out_w, awb);
  hipLaunchKernelGGL(k_seq, dim3(256), dim3(256), 0, stream,
                     awb, Wcat, gru_init, b_ih, b_hh, hbuf, flags, ctl, out_h);
}